// Round 6
// baseline (529.252 us; speedup 1.0000x reference)
//
#include <hip/hip_runtime.h>
#include <hip/hip_bf16.h>
#include <cmath>

typedef __bf16 bf16;
typedef __bf16 bf16x8 __attribute__((ext_vector_type(8)));
typedef float f32x4 __attribute__((ext_vector_type(4)));

#define BB 2
#define SS 2048
#define DD 1024
#define HH 16
#define WW 16
#define HDD 64
#define DFFD 4096
#define NTOK (BB*SS)

__device__ __forceinline__ float gelu_f(float x) {
    const float c = 0.7978845608028654f;  // sqrt(2/pi)
    float t = tanhf(c * (x + 0.044715f * x * x * x));
    return 0.5f * x * (1.0f + t);
}

// ---------------- LN row stats over fp32 rows: one block per row; {mean, rstd} ----------------
__global__ __launch_bounds__(256) void stats_kernel(
    const float* __restrict__ x, float2* __restrict__ stats)
{
    const int row = blockIdx.x, t = threadIdx.x;
    f32x4 v = *(const f32x4*)(x + (size_t)row * DD + t * 4);
    float s  = v[0] + v[1] + v[2] + v[3];
    float s2 = v[0]*v[0] + v[1]*v[1] + v[2]*v[2] + v[3]*v[3];
#pragma unroll
    for (int off = 32; off >= 1; off >>= 1) {
        s  += __shfl_xor(s,  off, 64);
        s2 += __shfl_xor(s2, off, 64);
    }
    __shared__ float red[8];
    const int wave = t >> 6;
    if ((t & 63) == 0) { red[wave] = s; red[4 + wave] = s2; }
    __syncthreads();
    if (t == 0) {
        float ts  = red[0] + red[1] + red[2] + red[3];
        float ts2 = red[4] + red[5] + red[6] + red[7];
        float mean = ts * (1.0f / DD);
        float var  = ts2 * (1.0f / DD) - mean * mean;
        stats[row] = make_float2(mean, rsqrtf(var + 1e-5f));
    }
}

// ---------------- MFMA GEMM: C[M,N] = LNopt(A)[M,K] @ W[N,K]^T + bias ----------------
// W/bias/lng/lnb/resid are fp32 (harness inputs / x1). A is fp32 (ASRC=1, with LN)
// or bf16 (ASRC=0). 128x128 tile, BK=32, 4 waves (2x2), 16x16x32 bf16 MFMA.
// ACT: 1=gelu. RESID: 2=add fp32 resid (may alias Cout when OUTF32=1: per-element
// read-before-write by the same thread). OUTF32: 1=fp32 out, 0=bf16 out.
template<int ASRC, int ACT, int RESID, int OUTF32>
__global__ __launch_bounds__(256) void gemm_bt(
    const void* __restrict__ A, const float* __restrict__ Bw,
    const float* __restrict__ bias,
    const float2* __restrict__ stats, const float* __restrict__ lng,
    const float* __restrict__ lnb,
    const float* resid, void* Cout, int N, int K)
{
    __shared__ bf16 As[128 * 32];
    __shared__ bf16 Bs[128 * 32];
    const int t = threadIdx.x;
    const int m0 = blockIdx.y * 128, n0 = blockIdx.x * 128;
    const int lane = t & 63, wave = t >> 6;
    const int wm = (wave & 1) * 64, wn = (wave >> 1) * 64;
    const int quad = lane >> 4, l16 = lane & 15;
    const int srow = t >> 2, scol = (t & 3) * 8;   // staging: 4 threads/row, 8 elems each

    const size_t rowA0 = (size_t)(m0 + srow) * K + scol;
    const size_t rowA1 = rowA0 + (size_t)64 * K;
    const float* Bp = Bw + (size_t)(n0 + srow) * K + scol;

    float mean0 = 0.f, rstd0 = 0.f, mean1 = 0.f, rstd1 = 0.f;
    if (ASRC == 1) {
        float2 s0 = stats[m0 + srow];      mean0 = s0.x; rstd0 = s0.y;
        float2 s1 = stats[m0 + srow + 64]; mean1 = s1.x; rstd1 = s1.y;
    }

    const f32x4 zero = {0.f, 0.f, 0.f, 0.f};
    f32x4 acc[4][4];
#pragma unroll
    for (int i = 0; i < 4; i++)
#pragma unroll
        for (int j = 0; j < 4; j++) acc[i][j] = zero;

    for (int k0 = 0; k0 < K; k0 += 32) {
        // ---- B staging: fp32 weights -> bf16 ----
        f32x4 b0lo = *(const f32x4*)(Bp + k0);
        f32x4 b0hi = *(const f32x4*)(Bp + k0 + 4);
        f32x4 b1lo = *(const f32x4*)(Bp + (size_t)64 * K + k0);
        f32x4 b1hi = *(const f32x4*)(Bp + (size_t)64 * K + k0 + 4);
        bf16x8 b0, b1;
#pragma unroll
        for (int i = 0; i < 4; i++) {
            b0[i] = (bf16)b0lo[i]; b0[4 + i] = (bf16)b0hi[i];
            b1[i] = (bf16)b1lo[i]; b1[4 + i] = (bf16)b1hi[i];
        }
        // ---- A staging ----
        bf16x8 a0, a1;
        if (ASRC == 1) {
            const float* Af = (const float*)A;
            f32x4 xlo = *(const f32x4*)(Af + rowA0 + k0);
            f32x4 xhi = *(const f32x4*)(Af + rowA0 + k0 + 4);
            f32x4 ylo = *(const f32x4*)(Af + rowA1 + k0);
            f32x4 yhi = *(const f32x4*)(Af + rowA1 + k0 + 4);
            f32x4 glo = *(const f32x4*)(lng + k0 + scol);
            f32x4 ghi = *(const f32x4*)(lng + k0 + scol + 4);
            f32x4 blo = *(const f32x4*)(lnb + k0 + scol);
            f32x4 bhi = *(const f32x4*)(lnb + k0 + scol + 4);
#pragma unroll
            for (int i = 0; i < 4; i++) {
                a0[i]     = (bf16)((xlo[i] - mean0) * rstd0 * glo[i] + blo[i]);
                a0[4 + i] = (bf16)((xhi[i] - mean0) * rstd0 * ghi[i] + bhi[i]);
                a1[i]     = (bf16)((ylo[i] - mean1) * rstd1 * glo[i] + blo[i]);
                a1[4 + i] = (bf16)((yhi[i] - mean1) * rstd1 * ghi[i] + bhi[i]);
            }
        } else {
            a0 = *(const bf16x8*)((const bf16*)A + rowA0 + k0);
            a1 = *(const bf16x8*)((const bf16*)A + rowA1 + k0);
        }
        __syncthreads();
        *(bf16x8*)(As + srow * 32 + scol) = a0;
        *(bf16x8*)(As + (srow + 64) * 32 + scol) = a1;
        *(bf16x8*)(Bs + srow * 32 + scol) = b0;
        *(bf16x8*)(Bs + (srow + 64) * 32 + scol) = b1;
        __syncthreads();
        bf16x8 af[4], bfr[4];
#pragma unroll
        for (int i = 0; i < 4; i++)
            af[i] = *(const bf16x8*)(As + (wm + i * 16 + l16) * 32 + quad * 8);
#pragma unroll
        for (int j = 0; j < 4; j++)
            bfr[j] = *(const bf16x8*)(Bs + (wn + j * 16 + l16) * 32 + quad * 8);
#pragma unroll
        for (int i = 0; i < 4; i++)
#pragma unroll
            for (int j = 0; j < 4; j++)
                acc[i][j] = __builtin_amdgcn_mfma_f32_16x16x32_bf16(af[i], bfr[j], acc[i][j], 0, 0, 0);
    }

#pragma unroll
    for (int i = 0; i < 4; i++) {
#pragma unroll
        for (int j = 0; j < 4; j++) {
            int col = n0 + wn + j * 16 + l16;
            float bv = bias[col];
#pragma unroll
            for (int r = 0; r < 4; r++) {
                int row = m0 + wm + i * 16 + quad * 4 + r;
                float val = acc[i][j][r] + bv;
                if (ACT == 1) val = gelu_f(val);
                size_t idx = (size_t)row * N + col;
                if (RESID == 2) val += resid[idx];
                if (OUTF32) ((float*)Cout)[idx] = val;
                else        ((bf16*)Cout)[idx] = (bf16)val;
            }
        }
    }
}

// ---------------- Sliding-window causal attention: one wave per (b,h,q) ----------------
// qkv [B,S,3D] bf16: q at col h*64+d, k at +D, v at +2D. lane = d (HD=64).
__global__ __launch_bounds__(256) void attn_kernel(
    const bf16* __restrict__ qkv, bf16* __restrict__ o)
{
    const int gw = blockIdx.x * 4 + (threadIdx.x >> 6);
    const int lane = threadIdx.x & 63;
    const int q = gw & (SS - 1);
    const int h = (gw >> 11) & (HH - 1);
    const int b = gw >> 15;
    const size_t rowstride = 3 * DD;
    const bf16* base = qkv + (size_t)b * SS * rowstride + h * HDD + lane;
    float qd = (float)base[(size_t)q * rowstride] * 0.125f;  // 1/sqrt(64)
    float kv[WW], vv[WW];
#pragma unroll
    for (int j = 0; j < WW; j++) {
        int key = q - (WW - 1) + j;
        int kc = key < 0 ? 0 : key;
        const bf16* kp = base + (size_t)kc * rowstride + DD;
        kv[j] = (float)kp[0];
        vv[j] = (float)kp[DD];
    }
    float sc[WW];
#pragma unroll
    for (int j = 0; j < WW; j++) {
        float p = qd * kv[j];
        p += __shfl_xor(p, 32, 64);
        p += __shfl_xor(p, 16, 64);
        p += __shfl_xor(p,  8, 64);
        p += __shfl_xor(p,  4, 64);
        p += __shfl_xor(p,  2, 64);
        p += __shfl_xor(p,  1, 64);
        sc[j] = (q - (WW - 1) + j >= 0) ? p : -1e30f;
    }
    float m = sc[0];
#pragma unroll
    for (int j = 1; j < WW; j++) m = fmaxf(m, sc[j]);
    float l = 0.f, od = 0.f;
#pragma unroll
    for (int j = 0; j < WW; j++) {
        float e = __expf(sc[j] - m);
        l += e;
        od += e * vv[j];
    }
    o[(size_t)(b * SS + q) * DD + h * HDD + lane] = (bf16)(od / l);
}

// ---------------- launch ----------------
extern "C" void kernel_launch(void* const* d_in, const int* in_sizes, int n_in,
                              void* d_out, int out_size, void* d_ws, size_t ws_size,
                              hipStream_t stream)
{
    (void)in_sizes; (void)n_in; (void)out_size; (void)ws_size;
    const float* x    = (const float*)d_in[0];
    const float* ln1g = (const float*)d_in[1];
    const float* ln1b = (const float*)d_in[2];
    const float* Wqkv = (const float*)d_in[3];
    const float* bqkv = (const float*)d_in[4];
    const float* Wout = (const float*)d_in[5];
    const float* bout = (const float*)d_in[6];
    const float* ln2g = (const float*)d_in[7];
    const float* ln2b = (const float*)d_in[8];
    const float* W1   = (const float*)d_in[9];
    const float* b1   = (const float*)d_in[10];
    const float* W2   = (const float*)d_in[11];
    const float* b2   = (const float*)d_in[12];

    // Workspace (peak 32 MiB + 64 KiB; R2's 56 MiB plan ran cleanly => ws >= 56 MiB):
    //   [0,32K) stats1 | [32K,64K) stats2 | buf at +64K:
    //   phase A: qkv bf16 24 MiB | o bf16 8 MiB
    //   phase B: h1 bf16 32 MiB overlays both (qkv, o dead)
    // x1 (fp32, 16 MB) lives exactly in d_out; MLP2 adds residual in-place
    // (each element read+written by one thread, read precedes write).
    const size_t KB = 1024;
    char* ws = (char*)d_ws;
    float2* stats1 = (float2*)ws;
    float2* stats2 = (float2*)(ws + 32 * KB);
    char* buf = ws + 64 * KB;
    bf16* qkv = (bf16*)buf;                        // 24 MiB
    bf16* o   = (bf16*)(buf + 24 * 1024 * KB);     // 8 MiB
    bf16* h1  = (bf16*)buf;                        // 32 MiB (phase B)
    float* x1 = (float*)d_out;                     // fp32 output buffer, 16 MB

    const dim3 blk(256);
    const dim3 gQKV(3 * DD / 128, NTOK / 128);
    const dim3 gOUT(DD / 128, NTOK / 128);
    const dim3 gMLP1(DFFD / 128, NTOK / 128);

    // 1. LN1 row stats over x (fp32)
    stats_kernel<<<NTOK, blk, 0, stream>>>(x, stats1);
    // 2. qkv = LN1(x) @ Wqkv^T + bqkv      (M=4096, N=3072, K=1024; bf16 out)
    gemm_bt<1, 0, 0, 0><<<gQKV, blk, 0, stream>>>(
        x, Wqkv, bqkv, stats1, ln1g, ln1b, nullptr, qkv, 3 * DD, DD);
    // 3. o = sliding-window attention(qkv)
    attn_kernel<<<BB * HH * SS / 4, blk, 0, stream>>>(qkv, o);
    // 4. x1 = x + o @ Wout^T + bout        (fp32, into d_out; M=4096, N=1024, K=1024)
    gemm_bt<0, 0, 2, 1><<<gOUT, blk, 0, stream>>>(
        o, Wout, bout, nullptr, nullptr, nullptr, x, x1, DD, DD);
    // 5. LN2 row stats over x1 (fp32)
    stats_kernel<<<NTOK, blk, 0, stream>>>(x1, stats2);
    // 6. h1 = gelu(LN2(x1) @ W1^T + b1)    (M=4096, N=4096, K=1024; bf16 out)
    gemm_bt<1, 1, 0, 0><<<gMLP1, blk, 0, stream>>>(
        x1, W1, b1, stats2, ln2g, ln2b, nullptr, h1, DFFD, DD);
    // 7. out = x1 + h1 @ W2^T + b2         (fp32, in-place in d_out; M=4096, N=1024, K=4096)
    gemm_bt<0, 0, 2, 1><<<gOUT, blk, 0, stream>>>(
        h1, W2, b2, nullptr, nullptr, nullptr, x1, x1, DD, DFFD);
}

// Round 7
// 411.783 us; speedup vs baseline: 1.2853x; 1.2853x over previous
//
#include <hip/hip_runtime.h>
#include <hip/hip_bf16.h>
#include <cmath>

typedef __bf16 bf16;
typedef __bf16 bf16x4 __attribute__((ext_vector_type(4)));
typedef __bf16 bf16x8 __attribute__((ext_vector_type(8)));
typedef float f32x4 __attribute__((ext_vector_type(4)));

#define BB 2
#define SS 2048
#define DD 1024
#define HH 16
#define WW 16
#define HDD 64
#define DFFD 4096
#define NTOK (BB*SS)

__device__ __forceinline__ float gelu_f(float x) {
    const float c = 0.7978845608028654f;  // sqrt(2/pi)
    float t = tanhf(c * (x + 0.044715f * x * x * x));
    return 0.5f * x * (1.0f + t);
}

// ---- async global->LDS 16B/lane. LDS dest = wave-uniform base + lane*16 (m104/m108). ----
__device__ __forceinline__ void glds16(const bf16* g, const bf16* l) {
    __builtin_amdgcn_global_load_lds(
        (const __attribute__((address_space(1))) void*)(uintptr_t)(const void*)g,
        (__attribute__((address_space(3))) void*)(unsigned)(uintptr_t)(const void*)l,
        16, 0, 0);
}

// ---------------- fp32 -> bf16 convert, 8 elems/thread ----------------
__global__ __launch_bounds__(256) void conv_kernel(
    const float* __restrict__ src, bf16* __restrict__ dst, int n8)
{
    int i = blockIdx.x * 256 + threadIdx.x;
    if (i >= n8) return;
    f32x4 a = *(const f32x4*)(src + (size_t)i * 8);
    f32x4 b = *(const f32x4*)(src + (size_t)i * 8 + 4);
    bf16x8 v;
#pragma unroll
    for (int j = 0; j < 4; j++) { v[j] = (bf16)a[j]; v[4 + j] = (bf16)b[j]; }
    *(bf16x8*)(dst + (size_t)i * 8) = v;
}

// ---------------- fused LayerNorm: fp32 row -> bf16 row, one block/row ----------------
__global__ __launch_bounds__(256) void ln_kernel(
    const float* __restrict__ x, const float* __restrict__ g, const float* __restrict__ b,
    bf16* __restrict__ out)
{
    const int row = blockIdx.x, t = threadIdx.x;
    f32x4 v = *(const f32x4*)(x + (size_t)row * DD + t * 4);
    float s  = v[0] + v[1] + v[2] + v[3];
    float s2 = v[0]*v[0] + v[1]*v[1] + v[2]*v[2] + v[3]*v[3];
#pragma unroll
    for (int off = 32; off >= 1; off >>= 1) {
        s  += __shfl_xor(s,  off, 64);
        s2 += __shfl_xor(s2, off, 64);
    }
    __shared__ float red[8];
    const int wave = t >> 6;
    if ((t & 63) == 0) { red[wave] = s; red[4 + wave] = s2; }
    __syncthreads();
    float ts  = red[0] + red[1] + red[2] + red[3];
    float ts2 = red[4] + red[5] + red[6] + red[7];
    float mean = ts * (1.0f / DD);
    float var  = ts2 * (1.0f / DD) - mean * mean;
    float rstd = rsqrtf(var + 1e-5f);
    f32x4 gv = *(const f32x4*)(g + t * 4);
    f32x4 bv = *(const f32x4*)(b + t * 4);
    bf16x4 o;
#pragma unroll
    for (int i = 0; i < 4; i++) o[i] = (bf16)((v[i] - mean) * rstd * gv[i] + bv[i]);
    *(bf16x4*)(out + (size_t)row * DD + t * 4) = o;
}

// ---------------- bf16 MFMA GEMM w/ global_load_lds: C[M,N] = A[M,K] @ W[N,K]^T + bias ----
// TM: 128 (waves 2x2, 4x4 frags) or 64 (waves 1x4, 4x2 frags). BN=128, BK=32, 256 thr.
// ACT: 1=gelu. RESID: 2=add fp32 resid (may alias fp32 Cout: same elem, same thread,
// read-before-write). OUTF32: 1=fp32 out, 0=bf16.
template<int TM, int ACT, int RESID, int OUTF32>
__global__ __launch_bounds__(256) void gemm_glds(
    const bf16* __restrict__ A, const bf16* __restrict__ Bw,
    const float* __restrict__ bias,
    const float* resid, void* __restrict__ Cout, int N, int K)
{
    constexpr int MI = 4;
    constexpr int NJ = (TM == 128) ? 4 : 2;
    __shared__ __align__(16) bf16 As[TM * 32];
    __shared__ __align__(16) bf16 Bs[128 * 32];
    const int t = threadIdx.x;
    const int m0 = blockIdx.y * TM, n0 = blockIdx.x * 128;
    const int lane = t & 63, w = t >> 6;
    const int wm = (TM == 128) ? (w & 1) * 64 : 0;
    const int wn = (TM == 128) ? (w >> 1) * 64 : w * 32;
    const int quad = lane >> 4, l16 = lane & 15;
    const int srow = t >> 2, scol = (t & 3) * 8;   // 4 lanes/row, 8 bf16 (16 B) each

    const bf16* Ag = A  + (size_t)(m0 + srow) * K + scol;
    const bf16* Bg = Bw + (size_t)(n0 + srow) * K + scol;
    const bf16* AsW = As + w * 512;   // wave-uniform LDS base (+i*2048 per 64-row chunk)
    const bf16* BsW = Bs + w * 512;

    const f32x4 zero = {0.f, 0.f, 0.f, 0.f};
    f32x4 acc[MI][NJ];
#pragma unroll
    for (int i = 0; i < MI; i++)
#pragma unroll
        for (int j = 0; j < NJ; j++) acc[i][j] = zero;

    for (int k0 = 0; k0 < K; k0 += 32) {
        __syncthreads();                       // all waves done reading previous tile
        glds16(Ag + k0, AsW);
        if (TM == 128) glds16(Ag + (size_t)64 * K + k0, AsW + 2048);
        glds16(Bg + k0, BsW);
        glds16(Bg + (size_t)64 * K + k0, BsW + 2048);
        __syncthreads();                       // drains vmcnt -> LDS tiles visible
        bf16x8 af[MI], bfr[NJ];
#pragma unroll
        for (int i = 0; i < MI; i++)
            af[i] = *(const bf16x8*)(As + (wm + i * 16 + l16) * 32 + quad * 8);
#pragma unroll
        for (int j = 0; j < NJ; j++)
            bfr[j] = *(const bf16x8*)(Bs + (wn + j * 16 + l16) * 32 + quad * 8);
#pragma unroll
        for (int i = 0; i < MI; i++)
#pragma unroll
            for (int j = 0; j < NJ; j++)
                acc[i][j] = __builtin_amdgcn_mfma_f32_16x16x32_bf16(af[i], bfr[j], acc[i][j], 0, 0, 0);
    }

#pragma unroll
    for (int i = 0; i < MI; i++) {
#pragma unroll
        for (int j = 0; j < NJ; j++) {
            int col = n0 + wn + j * 16 + l16;
            float bv = bias[col];
#pragma unroll
            for (int r = 0; r < 4; r++) {
                int row = m0 + wm + i * 16 + quad * 4 + r;
                float val = acc[i][j][r] + bv;
                if (ACT == 1) val = gelu_f(val);
                size_t idx = (size_t)row * N + col;
                if (RESID == 2) val += resid[idx];
                if (OUTF32) ((float*)Cout)[idx] = val;
                else        ((bf16*)Cout)[idx] = (bf16)val;
            }
        }
    }
}

// ---------------- Sliding-window causal attention: one wave per (b,h,q) ----------------
__global__ __launch_bounds__(256) void attn_kernel(
    const bf16* __restrict__ qkv, bf16* __restrict__ o)
{
    const int gw = blockIdx.x * 4 + (threadIdx.x >> 6);
    const int lane = threadIdx.x & 63;
    const int q = gw & (SS - 1);
    const int h = (gw >> 11) & (HH - 1);
    const int b = gw >> 15;
    const size_t rowstride = 3 * DD;
    const bf16* base = qkv + (size_t)b * SS * rowstride + h * HDD + lane;
    float qd = (float)base[(size_t)q * rowstride] * 0.125f;  // 1/sqrt(64)
    float kv[WW], vv[WW];
#pragma unroll
    for (int j = 0; j < WW; j++) {
        int key = q - (WW - 1) + j;
        int kc = key < 0 ? 0 : key;
        const bf16* kp = base + (size_t)kc * rowstride + DD;
        kv[j] = (float)kp[0];
        vv[j] = (float)kp[DD];
    }
    float sc[WW];
#pragma unroll
    for (int j = 0; j < WW; j++) {
        float p = qd * kv[j];
        p += __shfl_xor(p, 32, 64);
        p += __shfl_xor(p, 16, 64);
        p += __shfl_xor(p,  8, 64);
        p += __shfl_xor(p,  4, 64);
        p += __shfl_xor(p,  2, 64);
        p += __shfl_xor(p,  1, 64);
        sc[j] = (q - (WW - 1) + j >= 0) ? p : -1e30f;
    }
    float m = sc[0];
#pragma unroll
    for (int j = 1; j < WW; j++) m = fmaxf(m, sc[j]);
    float l = 0.f, od = 0.f;
#pragma unroll
    for (int j = 0; j < WW; j++) {
        float e = __expf(sc[j] - m);
        l += e;
        od += e * vv[j];
    }
    o[(size_t)(b * SS + q) * DD + h * HDD + lane] = (bf16)(od / l);
}

// ---------------- launch ----------------
extern "C" void kernel_launch(void* const* d_in, const int* in_sizes, int n_in,
                              void* d_out, int out_size, void* d_ws, size_t ws_size,
                              hipStream_t stream)
{
    (void)in_sizes; (void)n_in; (void)out_size; (void)ws_size;
    const float* x    = (const float*)d_in[0];
    const float* ln1g = (const float*)d_in[1];
    const float* ln1b = (const float*)d_in[2];
    const float* Wqkv = (const float*)d_in[3];
    const float* bqkv = (const float*)d_in[4];
    const float* Wout = (const float*)d_in[5];
    const float* bout = (const float*)d_in[6];
    const float* ln2g = (const float*)d_in[7];
    const float* ln2b = (const float*)d_in[8];
    const float* W1   = (const float*)d_in[9];
    const float* b1   = (const float*)d_in[10];
    const float* W2   = (const float*)d_in[11];
    const float* b2   = (const float*)d_in[12];

    // Workspace (exactly 56 MiB peak; R2's 56 MiB layout proved ws >= 56 MiB):
    //   [0,16M)  W region. Phase A: Wqkv_bf @0..6M, Wout_bf @6..8M.
    //            Phase B: W1_bf @0..8M, W2_bf @8..16M (conv after out-proj).
    //   [16,48M) P region. Phase A: qkv bf16 24 MiB. Phase B: h1 bf16 32 MiB.
    //   [48,56M) H region: h (LN1 out) -> o (attn out) -> xn (LN2 out), serially.
    //   x1 fp32 lives in d_out; MLP2 adds residual in-place (same elem, same thread).
    const size_t MB = (size_t)1 << 20;
    char* ws = (char*)d_ws;
    bf16* wqkv_bf = (bf16*)(ws);
    bf16* wout_bf = (bf16*)(ws + 6 * MB);
    bf16* w1_bf   = (bf16*)(ws);
    bf16* w2_bf   = (bf16*)(ws + 8 * MB);
    bf16* qkv     = (bf16*)(ws + 16 * MB);
    bf16* h1      = (bf16*)(ws + 16 * MB);
    bf16* hbuf    = (bf16*)(ws + 48 * MB);   // h, then o, then xn
    float* x1     = (float*)d_out;

    const dim3 blk(256);

    // Phase A: weights for QKV + out-proj
    conv_kernel<<<(3 * DD * DD / 8) / 256, blk, 0, stream>>>(Wqkv, wqkv_bf, 3 * DD * DD / 8);
    conv_kernel<<<(DD * DD / 8) / 256, blk, 0, stream>>>(Wout, wout_bf, DD * DD / 8);
    // h = LN1(x)
    ln_kernel<<<NTOK, blk, 0, stream>>>(x, ln1g, ln1b, hbuf);
    // qkv = h @ Wqkv^T + bqkv           (M=4096, N=3072, K=1024)
    gemm_glds<128, 0, 0, 0><<<dim3(24, 32), blk, 0, stream>>>(
        hbuf, wqkv_bf, bqkv, nullptr, qkv, 3 * DD, DD);
    // o = attention(qkv)  (o overwrites h — h dead)
    attn_kernel<<<BB * HH * SS / 4, blk, 0, stream>>>(qkv, hbuf);
    // x1 = x + o @ Wout^T + bout        (fp32 into d_out; M=4096, N=1024, K=1024)
    gemm_glds<64, 0, 2, 1><<<dim3(8, 64), blk, 0, stream>>>(
        hbuf, wout_bf, bout, x, x1, DD, DD);

    // Phase B: weights for MLP (overwrites phase-A weights; stream-ordered after out-proj)
    conv_kernel<<<(DFFD * DD / 8) / 256, blk, 0, stream>>>(W1, w1_bf, DFFD * DD / 8);
    conv_kernel<<<(DFFD * DD / 8) / 256, blk, 0, stream>>>(W2, w2_bf, DFFD * DD / 8);
    // xn = LN2(x1)   (xn overwrites o — o dead)
    ln_kernel<<<NTOK, blk, 0, stream>>>(x1, ln2g, ln2b, hbuf);
    // h1 = gelu(xn @ W1^T + b1)         (M=4096, N=4096, K=1024; h1 overwrites qkv)
    gemm_glds<128, 1, 0, 0><<<dim3(32, 32), blk, 0, stream>>>(
        hbuf, w1_bf, b1, nullptr, h1, DFFD, DD);
    // out = x1 + h1 @ W2^T + b2         (fp32 in-place in d_out; M=4096, N=1024, K=4096)
    gemm_glds<64, 0, 2, 1><<<dim3(8, 64), blk, 0, stream>>>(
        h1, w2_bf, b2, x1, x1, DD, DFFD);
}